// Round 4
// baseline (284.984 us; speedup 1.0000x reference)
//
#include <hip/hip_runtime.h>

// PillarScatter: feat [B=8, V=16384, C=64] f32, coords [B, V, 3] i32 (x,y,z)
// out [B, C, 512, 512] f32; out[b,c,y,x] = feat[b,v,c] for the LAST v mapping
// to (y,x) (numpy fancy-assign semantics), 0 elsewhere.
//
// v3: gather does 8 cells/thread with an 8x4 register transpose so each
// wave's per-channel store chunk is 2KB contiguous (was 1KB). Invalid cells
// read a zero-initialized __device__ array (.bss, never written -> stays
// zero across replays) -> no dummy memset dispatch.

typedef float f32x4 __attribute__((ext_vector_type(4)));
typedef int   i32x4 __attribute__((ext_vector_type(4)));

static constexpr int GX = 512;
static constexpr int GY = 512;
static constexpr int NCELL = GX * GY;   // 262144 = 2^18
static constexpr int B = 8;
static constexpr int V = 16384;         // 2^14
static constexpr int C = 64;

__device__ float g_zero_row[C];         // zero-initialized, read-only

__global__ __launch_bounds__(256) void ps_winner(const int* __restrict__ coords,
                                                 int* __restrict__ winner) {
    int idx = blockIdx.x * 256 + threadIdx.x;       // over B*V = 131072
    int x = coords[idx * 3 + 0];
    int y = coords[idx * 3 + 1];
    if ((unsigned)x >= (unsigned)GX || (unsigned)y >= (unsigned)GY) return;
    int b = idx >> 14;                              // idx / V
    int v = idx & (V - 1);
    atomicMax(&winner[(b << 18) + y * GX + x], v);  // last occurrence wins
}

__global__ __launch_bounds__(256) void ps_gather8(const f32x4* __restrict__ feat,
                                                  const i32x4* __restrict__ winner4,
                                                  float* __restrict__ out) {
    int tid = blockIdx.x * 256 + threadIdx.x;       // over B*NCELL/8 = 262144
    int b = tid >> 15;                              // tid / (NCELL/8)
    int cell8 = (tid & ((NCELL / 8) - 1)) * 8;      // first of 8 consecutive cells

    i32x4 wa = winner4[tid * 2 + 0];
    i32x4 wb = winner4[tid * 2 + 1];

    const f32x4* zr = (const f32x4*)g_zero_row;
    const f32x4* base = feat + ((long long)b << 18);  // + b*V*C/4

    const f32x4* r0 = (wa.x >= 0) ? base + ((long long)wa.x << 4) : zr;
    const f32x4* r1 = (wa.y >= 0) ? base + ((long long)wa.y << 4) : zr;
    const f32x4* r2 = (wa.z >= 0) ? base + ((long long)wa.z << 4) : zr;
    const f32x4* r3 = (wa.w >= 0) ? base + ((long long)wa.w << 4) : zr;
    const f32x4* r4 = (wb.x >= 0) ? base + ((long long)wb.x << 4) : zr;
    const f32x4* r5 = (wb.y >= 0) ? base + ((long long)wb.y << 4) : zr;
    const f32x4* r6 = (wb.z >= 0) ? base + ((long long)wb.z << 4) : zr;
    const f32x4* r7 = (wb.w >= 0) ? base + ((long long)wb.w << 4) : zr;

    float* obase = out + ((long long)b << 24) + cell8;  // b*C*NCELL + cell8

#pragma unroll
    for (int c4 = 0; c4 < 16; ++c4) {
        f32x4 f0 = r0[c4], f1 = r1[c4], f2 = r2[c4], f3 = r3[c4];
        f32x4 f4 = r4[c4], f5 = r5[c4], f6 = r6[c4], f7 = r7[c4];
        // channel c = c4*4+e: cells 0..3 in lo, 4..7 in hi
        f32x4 lo0 = {f0.x, f1.x, f2.x, f3.x}, hi0 = {f4.x, f5.x, f6.x, f7.x};
        f32x4 lo1 = {f0.y, f1.y, f2.y, f3.y}, hi1 = {f4.y, f5.y, f6.y, f7.y};
        f32x4 lo2 = {f0.z, f1.z, f2.z, f3.z}, hi2 = {f4.z, f5.z, f6.z, f7.z};
        f32x4 lo3 = {f0.w, f1.w, f2.w, f3.w}, hi3 = {f4.w, f5.w, f6.w, f7.w};
        float* p0 = obase + (long long)(c4 * 4 + 0) * NCELL;
        float* p1 = obase + (long long)(c4 * 4 + 1) * NCELL;
        float* p2 = obase + (long long)(c4 * 4 + 2) * NCELL;
        float* p3 = obase + (long long)(c4 * 4 + 3) * NCELL;
        __builtin_nontemporal_store(lo0, (f32x4*)p0);
        __builtin_nontemporal_store(hi0, (f32x4*)(p0 + 4));
        __builtin_nontemporal_store(lo1, (f32x4*)p1);
        __builtin_nontemporal_store(hi1, (f32x4*)(p1 + 4));
        __builtin_nontemporal_store(lo2, (f32x4*)p2);
        __builtin_nontemporal_store(hi2, (f32x4*)(p2 + 4));
        __builtin_nontemporal_store(lo3, (f32x4*)p3);
        __builtin_nontemporal_store(hi3, (f32x4*)(p3 + 4));
    }
}

extern "C" void kernel_launch(void* const* d_in, const int* in_sizes, int n_in,
                              void* d_out, int out_size, void* d_ws, size_t ws_size,
                              hipStream_t stream) {
    const float* feat  = (const float*)d_in[0];
    const int* coords  = (const int*)d_in[1];
    float* out         = (float*)d_out;
    int* winner        = (int*)d_ws;                 // B*NCELL ints = 8 MB

    (void)hipMemsetAsync(winner, 0xFF, (size_t)B * NCELL * sizeof(int), stream);
    ps_winner<<<(B * V) / 256, 256, 0, stream>>>(coords, winner);
    ps_gather8<<<(B * NCELL / 8) / 256, 256, 0, stream>>>(
        (const f32x4*)feat, (const i32x4*)winner, out);
}

// Round 5
// 115.194 us; speedup vs baseline: 2.4739x; 2.4739x over previous
//
#include <hip/hip_runtime.h>

// PillarScatter: feat [B=8, V=16384, C=64] f32, coords [B, V, 3] i32 (x,y,z)
// out [B, C, 512, 512] f32; out[b,c,y,x] = feat[b,v,c] for the LAST v mapping
// to (y,x) (numpy fancy-assign semantics), 0 elsewhere.
//
// v4 = v2 structure (4 cells/thread, 4x4 register transpose: each wave-level
// store instruction is a fully-contiguous 1KB chunk -- lane stride MUST equal
// store width, the v3 regression proved it) + v3's .bss zero row (drops the
// dummy-memset dispatch).

typedef float f32x4 __attribute__((ext_vector_type(4)));
typedef int   i32x4 __attribute__((ext_vector_type(4)));

static constexpr int GX = 512;
static constexpr int GY = 512;
static constexpr int NCELL = GX * GY;   // 262144 = 2^18
static constexpr int B = 8;
static constexpr int V = 16384;         // 2^14
static constexpr int C = 64;

__device__ float g_zero_row[C];         // zero-initialized .bss, never written

__global__ __launch_bounds__(256) void ps_winner(const int* __restrict__ coords,
                                                 int* __restrict__ winner) {
    int idx = blockIdx.x * 256 + threadIdx.x;       // over B*V = 131072
    int x = coords[idx * 3 + 0];
    int y = coords[idx * 3 + 1];
    if ((unsigned)x >= (unsigned)GX || (unsigned)y >= (unsigned)GY) return;
    int b = idx >> 14;                              // idx / V
    int v = idx & (V - 1);
    atomicMax(&winner[(b << 18) + y * GX + x], v);  // last occurrence wins
}

__global__ __launch_bounds__(256) void ps_gather4(const f32x4* __restrict__ feat,
                                                  const i32x4* __restrict__ winner4,
                                                  float* __restrict__ out) {
    int tid = blockIdx.x * 256 + threadIdx.x;       // over B*NCELL/4 = 524288
    int b = tid >> 16;                              // tid / (NCELL/4)
    int cell4 = (tid & ((NCELL / 4) - 1)) * 4;      // first of 4 consecutive cells

    i32x4 w = winner4[tid];

    const f32x4* zr = (const f32x4*)g_zero_row;
    const f32x4* base = feat + ((long long)b << 18);    // + b*V*C/4

    const f32x4* r0 = (w.x >= 0) ? base + ((long long)w.x << 4) : zr;
    const f32x4* r1 = (w.y >= 0) ? base + ((long long)w.y << 4) : zr;
    const f32x4* r2 = (w.z >= 0) ? base + ((long long)w.z << 4) : zr;
    const f32x4* r3 = (w.w >= 0) ? base + ((long long)w.w << 4) : zr;

    float* obase = out + ((long long)b << 24) + cell4;  // b*C*NCELL + cell4

#pragma unroll
    for (int c4 = 0; c4 < 16; ++c4) {
        f32x4 f0 = r0[c4];
        f32x4 f1 = r1[c4];
        f32x4 f2 = r2[c4];
        f32x4 f3 = r3[c4];
        // 4x4 transpose: channel c = c4*4+e gets {f0[e], f1[e], f2[e], f3[e]}
        f32x4 s0 = {f0.x, f1.x, f2.x, f3.x};
        f32x4 s1 = {f0.y, f1.y, f2.y, f3.y};
        f32x4 s2 = {f0.z, f1.z, f2.z, f3.z};
        f32x4 s3 = {f0.w, f1.w, f2.w, f3.w};
        f32x4* p0 = (f32x4*)(obase + (long long)(c4 * 4 + 0) * NCELL);
        f32x4* p1 = (f32x4*)(obase + (long long)(c4 * 4 + 1) * NCELL);
        f32x4* p2 = (f32x4*)(obase + (long long)(c4 * 4 + 2) * NCELL);
        f32x4* p3 = (f32x4*)(obase + (long long)(c4 * 4 + 3) * NCELL);
        __builtin_nontemporal_store(s0, p0);
        __builtin_nontemporal_store(s1, p1);
        __builtin_nontemporal_store(s2, p2);
        __builtin_nontemporal_store(s3, p3);
    }
}

extern "C" void kernel_launch(void* const* d_in, const int* in_sizes, int n_in,
                              void* d_out, int out_size, void* d_ws, size_t ws_size,
                              hipStream_t stream) {
    const float* feat  = (const float*)d_in[0];
    const int* coords  = (const int*)d_in[1];
    float* out         = (float*)d_out;
    int* winner        = (int*)d_ws;                 // B*NCELL ints = 8 MB

    (void)hipMemsetAsync(winner, 0xFF, (size_t)B * NCELL * sizeof(int), stream);
    ps_winner<<<(B * V) / 256, 256, 0, stream>>>(coords, winner);
    ps_gather4<<<(B * NCELL / 4) / 256, 256, 0, stream>>>(
        (const f32x4*)feat, (const i32x4*)winner, out);
}